// Round 8
// baseline (35.655 us; speedup 1.0000x reference)
//
#include <hip/hip_runtime.h>

// RandomResizedCrop N=128,C=3,H=W=256 fp32 — persistent blocks, software-
// pipelined stripes. R8: each block owns 4 stripes of one image; stripe i+1's
// 6 global row-loads are issued before stripe i's compute (loads always in
// flight). x-coords computed once. Barrier-free wave-private LDS segments.

constexpr int N_ = 128, C_ = 3, H_ = 256, W_ = 256, HW_ = H_ * W_;
constexpr int SEG_ = 264;   // skewed V-segment: x + (x>>5) maps 0..255 -> 0..262

typedef float f32x4 __attribute__((ext_vector_type(4)));

__device__ __forceinline__ void coord(float scale, float bias, float xf, int size,
                                      int& i0, float& w) {
    const float span = (float)size;
    const float two  = 2.0f * span;
    float xs  = (xf + 0.5f) * (2.0f / span) - 1.0f;
    float g   = scale * xs + bias;
    float pre = ((g + 1.0f) * span - 1.0f) * 0.5f;
    float t = fabsf(pre + 0.5f);
    t = t - two * floorf(t * (1.0f / two));   // exact fmod(t, 512), pow2 span
    t = (t > span) ? (two - t) : t;
    t -= 0.5f;
    t = fminf(fmaxf(t, 0.0f), span - 1.0f);
    float f = floorf(t);
    w  = t - f;
    i0 = (int)f;                              // i0 == size-1  =>  w == 0 exactly
}

__global__ __launch_bounds__(256)
void rrc_kernel(const float* __restrict__ in, const float* __restrict__ wh,
                float* __restrict__ out) {
    __shared__ float V[4 * C_ * SEG_];        // wave-private (row,ch) segments
    const int n   = blockIdx.x >> 4;          // image
    const int s0  = blockIdx.x & 15;          // stripes s0, s0+16, s0+32, s0+48
    const int tid = threadIdx.x;
    const int xq  = tid & 63;                 // x-quad: x = 4*xq..4*xq+3
    const int yl  = tid >> 6;                 // wave owns one row per stripe

    const float w_s = wh[n * 4 + 0];
    const float h_s = wh[n * 4 + 1];
    const float w_b = wh[n * 4 + 2];
    const float h_b = wh[n * 4 + 3];

    // x-coords + skewed gather offsets: stripe-invariant, computed ONCE.
    int offA[4], offB[4]; float wx[4];
#pragma unroll
    for (int j = 0; j < 4; ++j) {
        int i0;
        coord(w_s, w_b, (float)(xq * 4 + j), W_, i0, wx[j]);
        const int xb = min(i0 + 1, W_ - 1);   // wx==0 when clamped
        offA[j] = i0 + (i0 >> 5);
        offB[j] = xb + (xb >> 5);
    }

    const float* __restrict__ inN  = in  + (size_t)n * C_ * HW_;
    float* __restrict__       outN = out + (size_t)n * C_ * HW_;
    const int sx   = xq * 4;
    const int woff = sx + (xq >> 3);          // matches read skew for j=0..3
    float* const seg0 = &V[(yl * C_ + 0) * SEG_];
    float* const seg1 = &V[(yl * C_ + 1) * SEG_];
    float* const seg2 = &V[(yl * C_ + 2) * SEG_];

    // ---- prologue: stripe s0 ----
    int cy0; float cwy;
    coord(h_s, h_b, (float)(s0 * 4 + yl), H_, cy0, cwy);
    int cy1 = min(cy0 + 1, H_ - 1);
    f32x4 c0[C_], c1[C_], p0[C_], p1[C_];
#pragma unroll
    for (int c = 0; c < C_; ++c) {
        c0[c] = *reinterpret_cast<const f32x4*>(inN + c * HW_ + cy0 * W_ + sx);
        c1[c] = *reinterpret_cast<const f32x4*>(inN + c * HW_ + cy1 * W_ + sx);
    }

#pragma unroll
    for (int i = 0; i < 4; ++i) {
        int ny0 = 0, ny1 = 0; float nwy = 0.0f;
        if (i < 3) {                          // issue next stripe's loads NOW
            coord(h_s, h_b, (float)((s0 + 16 * (i + 1)) * 4 + yl), H_, ny0, nwy);
            ny1 = min(ny0 + 1, H_ - 1);
#pragma unroll
            for (int c = 0; c < C_; ++c) {
                p0[c] = *reinterpret_cast<const f32x4*>(inN + c * HW_ + ny0 * W_ + sx);
                p1[c] = *reinterpret_cast<const f32x4*>(inN + c * HW_ + ny1 * W_ + sx);
            }
        }

        // vlerp (registers) -> wave-private LDS segments, all channels
        {
            const f32x4 v0 = c0[0] + cwy * (c1[0] - c0[0]);
            const f32x4 v1 = c0[1] + cwy * (c1[1] - c0[1]);
            const f32x4 v2 = c0[2] + cwy * (c1[2] - c0[2]);
            *reinterpret_cast<f32x4*>(seg0 + woff) = v0;
            *reinterpret_cast<f32x4*>(seg1 + woff) = v1;
            *reinterpret_cast<f32x4*>(seg2 + woff) = v2;
        }

        // hlerp gathers + stores (same-wave DS ops are in-order; no barrier)
        const int y = (s0 + 16 * i) * 4 + yl;
#pragma unroll
        for (int c = 0; c < C_; ++c) {
            float* const seg = (c == 0) ? seg0 : (c == 1) ? seg1 : seg2;
            f32x4 o;
#pragma unroll
            for (int j = 0; j < 4; ++j) {
                const float a = seg[offA[j]];
                const float b = seg[offB[j]];
                o[j] = a + wx[j] * (b - a);
            }
            __builtin_nontemporal_store(o, reinterpret_cast<f32x4*>(
                outN + (c * H_ + y) * W_ + sx));
        }

        if (i < 3) {                          // rotate (register renames)
            cy0 = ny0; cy1 = ny1; cwy = nwy;
#pragma unroll
            for (int c = 0; c < C_; ++c) { c0[c] = p0[c]; c1[c] = p1[c]; }
        }
    }
}

extern "C" void kernel_launch(void* const* d_in, const int* in_sizes, int n_in,
                              void* d_out, int out_size, void* d_ws, size_t ws_size,
                              hipStream_t stream) {
    const float* in = (const float*)d_in[0];
    const float* wh = (const float*)d_in[1];
    float* out      = (float*)d_out;
    (void)in_sizes; (void)n_in; (void)out_size; (void)d_ws; (void)ws_size;

    dim3 grid(N_ * 16);  // 2048 persistent-ish blocks, 4 stripes each
    dim3 block(256);
    rrc_kernel<<<grid, block, 0, stream>>>(in, wh, out);
}

// Round 9
// 29.286 us; speedup vs baseline: 1.2175x; 1.2175x over previous
//
#include <hip/hip_runtime.h>

// RandomResizedCrop N=128,C=3,H=W=256 fp32 — R7 structure + XCD-pinned images.
// blockIdx remap: xcd = b&7 (HW round-robin); image n = (b&7) + 8*(slot>>6),
// stripe s = slot&63, slot = b>>3. All 64 blocks of an image run on ONE XCD
// -> its 786KB input lives in that L2; adjacent stripes share rows (h_s<=1).

constexpr int N_ = 128, C_ = 3, H_ = 256, W_ = 256, HW_ = H_ * W_;
constexpr int SEG_ = 264;   // skewed V-segment: x + (x>>5) maps 0..255 -> 0..262

typedef float f32x4 __attribute__((ext_vector_type(4)));

__device__ __forceinline__ void coord(float scale, float bias, float xf, int size,
                                      int& i0, float& w) {
    const float span = (float)size;
    const float two  = 2.0f * span;
    float xs  = (xf + 0.5f) * (2.0f / span) - 1.0f;
    float g   = scale * xs + bias;
    float pre = ((g + 1.0f) * span - 1.0f) * 0.5f;
    float t = fabsf(pre + 0.5f);
    t = t - two * floorf(t * (1.0f / two));   // exact fmod(t, 512), pow2 span
    t = (t > span) ? (two - t) : t;
    t -= 0.5f;
    t = fminf(fmaxf(t, 0.0f), span - 1.0f);
    float f = floorf(t);
    w  = t - f;
    i0 = (int)f;                              // i0 == size-1  =>  w == 0 exactly
}

__global__ __launch_bounds__(256)
void rrc_kernel(const float* __restrict__ in, const float* __restrict__ wh,
                float* __restrict__ out) {
    __shared__ float V[4 * C_ * SEG_];        // 12 wave-private segments, 12.7 KB
    const int b    = blockIdx.x;
    const int slot = b >> 3;
    const int n    = (b & 7) + 8 * (slot >> 6);   // image, pinned to XCD b&7
    const int ys   = (slot & 63) * 4;             // 4-row output stripe
    const int tid  = threadIdx.x;
    const int xq   = tid & 63;                // x-quad: x = 4*xq..4*xq+3
    const int yl   = tid >> 6;                // own output row = wave index

    const float w_s = wh[n * 4 + 0];
    const float h_s = wh[n * 4 + 1];
    const float w_b = wh[n * 4 + 2];
    const float h_b = wh[n * 4 + 3];

    // Own row's y-coordinate only.
    int iy0; float wy;
    coord(h_s, h_b, (float)(ys + yl), H_, iy0, wy);
    const int iy1 = min(iy0 + 1, H_ - 1);     // wy==0 when clamped

    // x-coords + skewed gather offsets (addr(x) = x + (x>>5), bijective).
    int offA[4], offB[4]; float wx[4];
#pragma unroll
    for (int j = 0; j < 4; ++j) {
        int i0;
        coord(w_s, w_b, (float)(xq * 4 + j), W_, i0, wx[j]);
        const int xb = min(i0 + 1, W_ - 1);   // wx==0 when clamped
        offA[j] = i0 + (i0 >> 5);
        offB[j] = xb + (xb >> 5);
    }

    // Preload all 3 channels' row pairs (6 coalesced f32x4 loads in flight).
    const float* __restrict__ inN = in + (size_t)n * C_ * HW_;
    f32x4 g0[C_], g1[C_];
#pragma unroll
    for (int c = 0; c < C_; ++c) {
        g0[c] = *reinterpret_cast<const f32x4*>(inN + c * HW_ + iy0 * W_ + xq * 4);
        g1[c] = *reinterpret_cast<const f32x4*>(inN + c * HW_ + iy1 * W_ + xq * 4);
    }

    float* __restrict__ outN = out + (size_t)n * C_ * HW_;
    const int segBase = yl * C_ * SEG_;
    const int woff    = xq * 4 + (xq >> 3);   // skewed write offset

#pragma unroll
    for (int c = 0; c < C_; ++c) {
        const f32x4 v = g0[c] + wy * (g1[c] - g0[c]);   // vlerp in registers
        float* seg = &V[segBase + c * SEG_];
        *reinterpret_cast<f32x4*>(seg + woff) = v;      // 1 ds_write_b128
        f32x4 o;
#pragma unroll
        for (int j = 0; j < 4; ++j) {
            const float a = seg[offA[j]];
            const float b2 = seg[offB[j]];
            o[j] = a + wx[j] * (b2 - a);                // hlerp
        }
        __builtin_nontemporal_store(o, reinterpret_cast<f32x4*>(
            outN + (c * H_ + ys + yl) * W_ + xq * 4));
    }
}

extern "C" void kernel_launch(void* const* d_in, const int* in_sizes, int n_in,
                              void* d_out, int out_size, void* d_ws, size_t ws_size,
                              hipStream_t stream) {
    const float* in = (const float*)d_in[0];
    const float* wh = (const float*)d_in[1];
    float* out      = (float*)d_out;
    (void)in_sizes; (void)n_in; (void)out_size; (void)d_ws; (void)ws_size;

    dim3 grid(N_ * 64);  // 8192 blocks; mapping in-kernel pins images to XCDs
    dim3 block(256);
    rrc_kernel<<<grid, block, 0, stream>>>(in, wh, out);
}